// Round 1
// baseline (91.458 us; speedup 1.0000x reference)
//
#include <hip/hip_runtime.h>

// Problem geometry (fixed by setup_inputs):
//   img: (1080, 1920, 3) fp32; x = img[3:-3] -> (1074, 1920, 3)
//   vertical median, window 5, symmetric padding along axis 0.
#define N_ROWS 1074          // output rows
#define ROW_F  5760          // floats per row (1920*3)
#define ROW_V4 1440          // float4 per row

__device__ __forceinline__ void cswap(float& a, float& b) {
    float lo = fminf(a, b);
    b = fmaxf(a, b);
    a = lo;
}

// Devillard opt_med5: 7 compare-exchanges, result in p2.
__device__ __forceinline__ float med5(float p0, float p1, float p2, float p3, float p4) {
    cswap(p0, p1); cswap(p3, p4); cswap(p0, p3);
    cswap(p1, p4); cswap(p1, p2); cswap(p2, p3);
    cswap(p1, p2);
    return p2;
}

__global__ __launch_bounds__(256)
void VerticalMedian_54262616818099_kernel(const float* __restrict__ img,
                                          float* __restrict__ out) {
    const int c4 = blockIdx.x * 256 + threadIdx.x;   // float4 column index
    if (c4 >= ROW_V4) return;
    const int i = blockIdx.y;                        // output row

    const float4* __restrict__ in4 = (const float4*)img;

    float4 v[5];
#pragma unroll
    for (int k = 0; k < 5; ++k) {
        int j = i + k - 2;                 // window row in cropped coords
        j = (j < 0) ? (-1 - j) : j;        // symmetric reflect (top)
        j = (j >= N_ROWS) ? (2 * N_ROWS - 1 - j) : j;  // symmetric reflect (bottom)
        v[k] = in4[(size_t)(j + 3) * ROW_V4 + c4];     // +3: crop offset into img
    }

    float4 r;
    r.x = med5(v[0].x, v[1].x, v[2].x, v[3].x, v[4].x);
    r.y = med5(v[0].y, v[1].y, v[2].y, v[3].y, v[4].y);
    r.z = med5(v[0].z, v[1].z, v[2].z, v[3].z, v[4].z);
    r.w = med5(v[0].w, v[1].w, v[2].w, v[3].w, v[4].w);

    ((float4*)out)[(size_t)i * ROW_V4 + c4] = r;
}

extern "C" void kernel_launch(void* const* d_in, const int* in_sizes, int n_in,
                              void* d_out, int out_size, void* d_ws, size_t ws_size,
                              hipStream_t stream) {
    const float* img = (const float*)d_in[0];
    // d_in[1] = mask (unused by reference output), d_in[2] = vertical_size (fixed 5)
    float* out = (float*)d_out;

    dim3 block(256, 1, 1);
    dim3 grid((ROW_V4 + 255) / 256, N_ROWS, 1);   // (6, 1074)
    VerticalMedian_54262616818099_kernel<<<grid, block, 0, stream>>>(img, out);
}

// Round 2
// 83.586 us; speedup vs baseline: 1.0942x; 1.0942x over previous
//
#include <hip/hip_runtime.h>

// Problem geometry (fixed by setup_inputs):
//   img: (1080, 1920, 3) fp32; x = img[3:-3] -> (1074, 1920, 3)
//   vertical median, window 5, symmetric padding along axis 0.
#define N_ROWS 1074          // output rows
#define ROW_V4 1440          // float4 per row (1920*3/4)
#define RPB    8             // output rows per thread (rolling window)

__device__ __forceinline__ void cswap(float& a, float& b) {
    float lo = fminf(a, b);
    b = fmaxf(a, b);
    a = lo;
}

// Devillard opt_med5: 7 compare-exchanges, result in p2.
__device__ __forceinline__ float med5(float p0, float p1, float p2, float p3, float p4) {
    cswap(p0, p1); cswap(p3, p4); cswap(p0, p3);
    cswap(p1, p4); cswap(p1, p2); cswap(p2, p3);
    cswap(p1, p2);
    return p2;
}

__device__ __forceinline__ float4 med5v(const float4& a, const float4& b,
                                        const float4& c, const float4& d,
                                        const float4& e) {
    float4 r;
    r.x = med5(a.x, b.x, c.x, d.x, e.x);
    r.y = med5(a.y, b.y, c.y, d.y, e.y);
    r.z = med5(a.z, b.z, c.z, d.z, e.z);
    r.w = med5(a.w, b.w, c.w, d.w, e.w);
    return r;
}

__global__ __launch_bounds__(256)
void VerticalMedian_54262616818099_kernel(const float* __restrict__ img,
                                          float* __restrict__ out) {
    const int c4 = blockIdx.x * 256 + threadIdx.x;   // float4 column index
    if (c4 >= ROW_V4) return;
    const int i0 = blockIdx.y * RPB;                 // first output row of strip

    const float4* __restrict__ in4 = (const float4*)img + c4;
    float4* __restrict__ o4 = (float4*)out + c4;

    // Load one (reflected) window row; +3 crops img[3:-3].
    auto ld = [&](int j) -> float4 {
        j = (j < 0) ? (-1 - j) : j;                    // symmetric reflect top
        j = (j >= N_ROWS) ? (2 * N_ROWS - 1 - j) : j;  // symmetric reflect bottom
        return in4[(size_t)(j + 3) * ROW_V4];
    };

    // Prime 4 rows of the 5-row rolling window.
    float4 w0 = ld(i0 - 2), w1 = ld(i0 - 1), w2 = ld(i0), w3 = ld(i0 + 1);

#pragma unroll
    for (int r = 0; r < RPB; ++r) {
        const int i = i0 + r;
        if (i >= N_ROWS) break;                        // partial last strip
        float4 w4 = ld(i + 2);                         // 1 new load per output row
        o4[(size_t)i * ROW_V4] = med5v(w0, w1, w2, w3, w4);
        w0 = w1; w1 = w2; w2 = w3; w3 = w4;
    }
}

extern "C" void kernel_launch(void* const* d_in, const int* in_sizes, int n_in,
                              void* d_out, int out_size, void* d_ws, size_t ws_size,
                              hipStream_t stream) {
    const float* img = (const float*)d_in[0];
    // d_in[1] = mask (unused by reference output), d_in[2] = vertical_size (fixed 5)
    float* out = (float*)d_out;

    dim3 block(256, 1, 1);
    dim3 grid((ROW_V4 + 255) / 256,                    // 6 column chunks
              (N_ROWS + RPB - 1) / RPB, 1);            // 135 row strips
    VerticalMedian_54262616818099_kernel<<<grid, block, 0, stream>>>(img, out);
}